// Round 7
// baseline (201.487 us; speedup 1.0000x reference)
//
#include <hip/hip_runtime.h>
#include <math.h>

#define B 8
#define D 512
#define N 4096
#define HEADS 8
#define DH 64
#define HID 512
#define O3 1536
#define KDIM 512
#define SCALE 0.125f
#define SQRT_D 22.62741699796952f

typedef __attribute__((ext_vector_type(4))) float f32x4;
typedef __attribute__((ext_vector_type(8))) short bf16x8;

static __device__ __forceinline__ unsigned short f2bf(float f) {
    unsigned int u = __float_as_uint(f);
    unsigned int r = (u + 0x7fffu + ((u >> 16) & 1u)) >> 16;
    return (unsigned short)r;
}

static __device__ __forceinline__ float bf2f(unsigned short u) {
    return __uint_as_float((unsigned int)u << 16);
}

static __device__ __forceinline__ void gload_lds16(const void* g, void* l) {
    __builtin_amdgcn_global_load_lds(
        (const __attribute__((address_space(1))) unsigned int*)g,
        (__attribute__((address_space(3))) unsigned int*)l, 16, 0, 0);
}

// ---------------------------------------------------------------------------
// cvt_w: w_qkv fp32 [1536*512] -> bf16
// ---------------------------------------------------------------------------
__global__ __launch_bounds__(256) void cvt_w(const float* __restrict__ w,
                                             unsigned short* __restrict__ wb) {
    int i = (blockIdx.x * 256 + threadIdx.x) * 4;
    float4 v = *(const float4*)(w + i);
    __align__(8) unsigned short o[4] = {f2bf(v.x), f2bf(v.y), f2bf(v.z), f2bf(v.w)};
    *(uint2*)(wb + i) = *(const uint2*)o;
}

// ---------------------------------------------------------------------------
// transpose_x: x fp32 [b][512][4096] -> xT bf16 [b][4096][512]
// ---------------------------------------------------------------------------
__global__ __launch_bounds__(256) void transpose_x(const float* __restrict__ x,
                                                   unsigned short* __restrict__ xT) {
    __shared__ float tile[64][65];
    const int n0 = blockIdx.x * 64, d0 = blockIdx.y * 64, b = blockIdx.z;
    const float* xb = x + (size_t)b * D * N;
    unsigned short* xTb = xT + (size_t)b * N * KDIM;
    const int t = threadIdx.x;
    const int r = t >> 4, c4 = (t & 15) * 4;
#pragma unroll
    for (int i = 0; i < 4; ++i) {
        int row = r + i * 16;
        float4 v = *(const float4*)(xb + (size_t)(d0 + row) * N + n0 + c4);
        tile[row][c4 + 0] = v.x;
        tile[row][c4 + 1] = v.y;
        tile[row][c4 + 2] = v.z;
        tile[row][c4 + 3] = v.w;
    }
    __syncthreads();
#pragma unroll
    for (int pass = 0; pass < 2; ++pass) {
        int orow = (t >> 3) + pass * 32;
        int oc = (t & 7) * 8;
        __align__(16) unsigned short o[8];
#pragma unroll
        for (int e = 0; e < 8; ++e) o[e] = f2bf(tile[oc + e][orow]);
        *(uint4*)(xTb + (size_t)(n0 + orow) * KDIM + d0 + oc) = *(const uint4*)o;
    }
}

// ---------------------------------------------------------------------------
// shared GEMM core: 128x128 tile, BK=64, 4 waves, mfma_f32_16x16x32_bf16
// ---------------------------------------------------------------------------
#define GEMM_CORE(A_PTR, BT_PTR, ACC)                                              \
    __shared__ __align__(16) unsigned short As[128 * 64];                          \
    __shared__ __align__(16) unsigned short Bs[128 * 64];                          \
    const int t = threadIdx.x;                                                     \
    const int lane = t & 63;                                                       \
    const int wid = t >> 6;                                                        \
    const int wm = wid >> 1, wn = wid & 1;                                         \
    int prow[4], coff[4];                                                          \
    _Pragma("unroll") for (int i = 0; i < 4; ++i) {                                \
        int p = i * 4096 + t * 16;                                                 \
        int pr = p >> 7;                                                           \
        int pc = (p >> 4) & 7;                                                     \
        prow[i] = pr;                                                              \
        coff[i] = (pc ^ (pr & 7)) * 8;                                             \
    }                                                                              \
    int aoff[4][2], boff[4][2];                                                    \
    _Pragma("unroll") for (int m = 0; m < 4; ++m) {                                \
        int arow = wm * 64 + m * 16 + (lane & 15);                                 \
        int brow = wn * 64 + m * 16 + (lane & 15);                                 \
        _Pragma("unroll") for (int s = 0; s < 2; ++s) {                            \
            int chunk = s * 4 + (lane >> 4);                                       \
            aoff[m][s] = arow * 128 + ((chunk ^ (arow & 7)) << 4);                 \
            boff[m][s] = brow * 128 + ((chunk ^ (brow & 7)) << 4);                 \
        }                                                                          \
    }                                                                              \
    f32x4 ACC[4][4] = {};                                                          \
    for (int k0 = 0; k0 < KDIM; k0 += 64) {                                        \
        _Pragma("unroll") for (int i = 0; i < 4; ++i)                              \
            gload_lds16(A_PTR + (size_t)(row0 + prow[i]) * KDIM + k0 + coff[i],    \
                        (char*)As + i * 4096 + t * 16);                            \
        _Pragma("unroll") for (int i = 0; i < 4; ++i)                              \
            gload_lds16(BT_PTR + (size_t)(col0 + prow[i]) * KDIM + k0 + coff[i],   \
                        (char*)Bs + i * 4096 + t * 16);                            \
        __syncthreads();                                                           \
        bf16x8 af[4][2], bfr[4][2];                                                \
        _Pragma("unroll") for (int m = 0; m < 4; ++m)                              \
            _Pragma("unroll") for (int s = 0; s < 2; ++s) {                        \
                af[m][s] = *(const bf16x8*)((const char*)As + aoff[m][s]);         \
                bfr[m][s] = *(const bf16x8*)((const char*)Bs + boff[m][s]);        \
            }                                                                      \
        _Pragma("unroll") for (int s = 0; s < 2; ++s)                              \
            _Pragma("unroll") for (int m = 0; m < 4; ++m)                          \
                _Pragma("unroll") for (int n = 0; n < 4; ++n)                      \
                    ACC[m][n] = __builtin_amdgcn_mfma_f32_16x16x32_bf16(           \
                        af[m][s], bfr[n][s], ACC[m][n], 0, 0, 0);                  \
        __syncthreads();                                                           \
    }

// ---------------------------------------------------------------------------
// gemm_kv2: k,v = w_qkv[512:1536] @ x.
// k rows (blockIdx.y<4): write exp(k) bf16 + atomicAdd per-row sum(exp).
// v rows: plain bf16.
// ---------------------------------------------------------------------------
__global__ __launch_bounds__(256) void gemm_kv2(const unsigned short* __restrict__ Aw,
                                                const unsigned short* __restrict__ BTall,
                                                unsigned short* __restrict__ kvall,
                                                float* __restrict__ ksum) {
    const int b = blockIdx.z;
    const unsigned short* A = Aw;
    const unsigned short* BT = BTall + (size_t)b * N * KDIM;
    unsigned short* C = kvall + (size_t)b * 1024 * N;
    const int row0 = blockIdx.y * 128;
    const int col0 = blockIdx.x * 128;
    GEMM_CORE(A, BT, acc)
    if (blockIdx.y < 4) {
#pragma unroll
        for (int m = 0; m < 4; ++m) {
            int row_b = row0 + wm * 64 + m * 16 + (lane >> 4) * 4;
#pragma unroll
            for (int r = 0; r < 4; ++r) {
                float rs = 0.f;
#pragma unroll
                for (int n = 0; n < 4; ++n) {
                    int col = col0 + wn * 64 + n * 16 + (lane & 15);
                    float e = __expf(acc[m][n][r]);
                    unsigned short bf = f2bf(e);
                    C[(size_t)(row_b + r) * N + col] = bf;
                    rs += bf2f(bf);
                }
                rs += __shfl_xor(rs, 1);
                rs += __shfl_xor(rs, 2);
                rs += __shfl_xor(rs, 4);
                rs += __shfl_xor(rs, 8);
                if ((lane & 15) == 0) atomicAdd(&ksum[b * 512 + row_b + r], rs);
            }
        }
    } else {
#pragma unroll
        for (int m = 0; m < 4; ++m) {
            int row_b = row0 + wm * 64 + m * 16 + (lane >> 4) * 4;
#pragma unroll
            for (int n = 0; n < 4; ++n) {
                int col = col0 + wn * 64 + n * 16 + (lane & 15);
#pragma unroll
                for (int r = 0; r < 4; ++r)
                    C[(size_t)(row_b + r) * N + col] = f2bf(acc[m][n][r]);
            }
        }
    }
}

// ---------------------------------------------------------------------------
// gemm_q_sm: q GEMM + fused softmax over d per head -> qT bf16 [b][n][512]
// ---------------------------------------------------------------------------
__global__ __launch_bounds__(256) void gemm_q_sm(const unsigned short* __restrict__ Aw,
                                                 const unsigned short* __restrict__ BTall,
                                                 unsigned short* __restrict__ qT) {
    const int b = blockIdx.z;
    const unsigned short* A = Aw;
    const unsigned short* BT = BTall + (size_t)b * N * KDIM;
    const int row0 = blockIdx.y * 128;
    const int col0 = blockIdx.x * 128;
    GEMM_CORE(A, BT, acc)
    const int h = blockIdx.y * 2 + wm;
    const int g = lane >> 4;
#pragma unroll
    for (int nf = 0; nf < 4; ++nf) {
        float mx = -1e30f;
#pragma unroll
        for (int m = 0; m < 4; ++m)
#pragma unroll
            for (int r = 0; r < 4; ++r) mx = fmaxf(mx, acc[m][nf][r]);
        mx = fmaxf(mx, __shfl_xor(mx, 16));
        mx = fmaxf(mx, __shfl_xor(mx, 32));
        float e[16];
        float s = 0.f;
#pragma unroll
        for (int m = 0; m < 4; ++m)
#pragma unroll
            for (int r = 0; r < 4; ++r) {
                e[m * 4 + r] = __expf(acc[m][nf][r] - mx);
                s += e[m * 4 + r];
            }
        s += __shfl_xor(s, 16);
        s += __shfl_xor(s, 32);
        float rs = SCALE / s;
        int n = col0 + wn * 64 + nf * 16 + (lane & 15);
        unsigned short* dst = qT + ((size_t)b * N + n) * KDIM + h * 64 + g * 4;
#pragma unroll
        for (int m = 0; m < 4; ++m) {
            __align__(8) unsigned short o4[4] = {f2bf(e[m * 4 + 0] * rs), f2bf(e[m * 4 + 1] * rs),
                                                 f2bf(e[m * 4 + 2] * rs), f2bf(e[m * 4 + 3] * rs)};
            *(uint2*)(dst + m * 16) = *(const uint2*)o4;
        }
    }
}

// ---------------------------------------------------------------------------
// context_mfma2: ctx[b,h,d,e] += sum_{n chunk} kexp[d,n] * v[e,n]
// Both operands bf16 in kvb, staged via global_load_lds (swizzled source).
// ---------------------------------------------------------------------------
__global__ __launch_bounds__(256) void context_mfma2(const unsigned short* __restrict__ kvb,
                                                     float* __restrict__ ctx) {
    const int ch = blockIdx.x, h = blockIdx.y, b = blockIdx.z;
    const int K0 = ch * 512;
    const unsigned short* kbase = kvb + ((size_t)b * 1024 + h * DH) * (size_t)N + K0;
    const unsigned short* vbase = kvb + ((size_t)b * 1024 + 512 + h * DH) * (size_t)N + K0;

    __shared__ __align__(16) unsigned short Ks[64 * 64];
    __shared__ __align__(16) unsigned short Vs[64 * 64];

    const int t = threadIdx.x;
    const int lane = t & 63;
    const int wv = t >> 6;

    int srow[2], scoff[2];
#pragma unroll
    for (int i = 0; i < 2; ++i) {
        int p = i * 4096 + t * 16;
        int pr = p >> 7;
        int pc = (p >> 4) & 7;
        srow[i] = pr;
        scoff[i] = (pc ^ (pr & 7)) * 8;
    }

    const int ar = wv * 16 + (lane & 15);
    int aoff[2], boff[4][2];
#pragma unroll
    for (int s = 0; s < 2; ++s) {
        int chunk = s * 4 + (lane >> 4);
        aoff[s] = ar * 128 + ((chunk ^ (ar & 7)) << 4);
#pragma unroll
        for (int nf = 0; nf < 4; ++nf) {
            int br = nf * 16 + (lane & 15);
            boff[nf][s] = br * 128 + ((chunk ^ (br & 7)) << 4);
        }
    }

    f32x4 acc[4] = {};

    for (int k0 = 0; k0 < 512; k0 += 64) {
#pragma unroll
        for (int i = 0; i < 2; ++i) {
            gload_lds16(kbase + (size_t)srow[i] * N + k0 + scoff[i],
                        (char*)Ks + i * 4096 + t * 16);
            gload_lds16(vbase + (size_t)srow[i] * N + k0 + scoff[i],
                        (char*)Vs + i * 4096 + t * 16);
        }
        __syncthreads();

        bf16x8 av[2], bv[4][2];
#pragma unroll
        for (int s = 0; s < 2; ++s) {
            av[s] = *(const bf16x8*)((const char*)Ks + aoff[s]);
#pragma unroll
            for (int nf = 0; nf < 4; ++nf)
                bv[nf][s] = *(const bf16x8*)((const char*)Vs + boff[nf][s]);
        }
#pragma unroll
        for (int s = 0; s < 2; ++s)
#pragma unroll
            for (int nf = 0; nf < 4; ++nf)
                acc[nf] = __builtin_amdgcn_mfma_f32_16x16x32_bf16(av[s], bv[nf][s], acc[nf], 0, 0, 0);
        __syncthreads();
    }

    float* cbase = ctx + ((size_t)(b * HEADS + h)) * DH * DH;
    const int drow = wv * 16 + (lane >> 4) * 4;
#pragma unroll
    for (int nf = 0; nf < 4; ++nf) {
        int e = nf * 16 + (lane & 15);
#pragma unroll
        for (int rr = 0; rr < 4; ++rr)
            atomicAdd(&cbase[(drow + rr) * DH + e], acc[nf][rr]);
    }
}

// ---------------------------------------------------------------------------
// fold_wout3: per (b,h): W2[o][d] = sum_e w_out[o][h*64+e] * ctx[b,h,d,e]/ksum[d]
// ---------------------------------------------------------------------------
__global__ __launch_bounds__(256) void fold_wout3(const float* __restrict__ w_out,
                                                  const float* __restrict__ ctx,
                                                  const float* __restrict__ ksum,
                                                  unsigned short* __restrict__ w2) {
    const int ot = blockIdx.x, h = blockIdx.y, b = blockIdx.z;
    __shared__ __align__(16) unsigned short As[128 * 64];
    __shared__ __align__(16) unsigned short Bs[64 * 64];
    const int t = threadIdx.x;
    const int lane = t & 63;
    const int wv = t >> 6;

#pragma unroll
    for (int i = 0; i < 8; ++i) {
        int lin = t + i * 256;
        int r = lin >> 4;
        int c4 = (lin & 15) * 4;
        float4 v = *(const float4*)(w_out + (size_t)(ot * 128 + r) * HID + h * 64 + c4);
        __align__(8) unsigned short o4[4] = {f2bf(v.x), f2bf(v.y), f2bf(v.z), f2bf(v.w)};
        int chunk = c4 >> 3;
        int off = (c4 & 7) * 2;
        *(uint2*)((char*)As + r * 128 + ((chunk ^ (r & 7)) << 4) + off) = *(const uint2*)o4;
    }
    const float* cb = ctx + ((size_t)(b * HEADS + h)) * DH * DH;
    const float* ks = ksum + b * 512 + h * 64;
#pragma unroll
    for (int i = 0; i < 4; ++i) {
        int lin = t + i * 256;
        int r = lin >> 4;
        int c4 = (lin & 15) * 4;
        float inv = 1.0f / ks[r];
        float4 v = *(const float4*)(cb + (size_t)r * DH + c4);
        __align__(8) unsigned short o4[4] = {f2bf(v.x * inv), f2bf(v.y * inv),
                                             f2bf(v.z * inv), f2bf(v.w * inv)};
        int chunk = c4 >> 3;
        int off = (c4 & 7) * 2;
        *(uint2*)((char*)Bs + r * 128 + ((chunk ^ (r & 7)) << 4) + off) = *(const uint2*)o4;
    }
    __syncthreads();

    f32x4 acc[2][4] = {};
#pragma unroll
    for (int s = 0; s < 2; ++s) {
        int chunk = s * 4 + (lane >> 4);
        bf16x8 bf[4];
#pragma unroll
        for (int nf = 0; nf < 4; ++nf) {
            int brow = nf * 16 + (lane & 15);
            bf[nf] = *(const bf16x8*)((const char*)Bs + brow * 128 + ((chunk ^ (brow & 7)) << 4));
        }
#pragma unroll
        for (int mm = 0; mm < 2; ++mm) {
            int arow = (wv * 2 + mm) * 16 + (lane & 15);
            bf16x8 a = *(const bf16x8*)((const char*)As + arow * 128 + ((chunk ^ (arow & 7)) << 4));
#pragma unroll
            for (int nf = 0; nf < 4; ++nf)
                acc[mm][nf] = __builtin_amdgcn_mfma_f32_16x16x32_bf16(a, bf[nf], acc[mm][nf], 0, 0, 0);
        }
    }

#pragma unroll
    for (int mm = 0; mm < 2; ++mm) {
        int o_base = ot * 128 + (wv * 2 + mm) * 16 + (lane >> 4) * 4;
#pragma unroll
        for (int nf = 0; nf < 4; ++nf) {
            int d = nf * 16 + (lane & 15);
#pragma unroll
            for (int rr = 0; rr < 4; ++rr)
                w2[((size_t)(b * D) + o_base + rr) * D + h * 64 + d] = f2bf(acc[mm][nf][rr]);
        }
    }
}

// ---------------------------------------------------------------------------
// gemm_y: y = W2[b] @ qT + bias -> bf16 yb, plus per-column sum((y)^2) atomics
// ---------------------------------------------------------------------------
__global__ __launch_bounds__(256) void gemm_y(const unsigned short* __restrict__ w2all,
                                              const unsigned short* __restrict__ qTall,
                                              const float* __restrict__ bias,
                                              unsigned short* __restrict__ yball,
                                              float* __restrict__ colsum) {
    const int b = blockIdx.z;
    const unsigned short* A = w2all + (size_t)b * D * D;
    const unsigned short* BT = qTall + (size_t)b * N * KDIM;
    unsigned short* yb = yball + (size_t)b * D * N;
    const int row0 = blockIdx.y * 128;
    const int col0 = blockIdx.x * 128;
    GEMM_CORE(A, BT, acc)

    float csum[4] = {0.f, 0.f, 0.f, 0.f};
#pragma unroll
    for (int m = 0; m < 4; ++m) {
        int row_b = row0 + wm * 64 + m * 16 + (lane >> 4) * 4;
#pragma unroll
        for (int r = 0; r < 4; ++r) {
            float bv = bias[row_b + r];
#pragma unroll
            for (int n = 0; n < 4; ++n) {
                int col = col0 + wn * 64 + n * 16 + (lane & 15);
                float e = acc[m][n][r] + bv;
                unsigned short bf = f2bf(e);
                yb[(size_t)(row_b + r) * N + col] = bf;
                float er = bf2f(bf);
                csum[n] += er * er;
            }
        }
    }
#pragma unroll
    for (int n = 0; n < 4; ++n) {
        csum[n] += __shfl_xor(csum[n], 16);
        csum[n] += __shfl_xor(csum[n], 32);
    }
    if (lane < 16) {
#pragma unroll
        for (int n = 0; n < 4; ++n) {
            int col = col0 + wn * 64 + n * 16 + lane;
            atomicAdd(&colsum[b * N + col], csum[n]);
        }
    }
}

// ---------------------------------------------------------------------------
// rmsnorm3: out[b][o][n] = yb[b][o][n] * SQRT_D/max(sqrt(colsum),eps) * g[o]
// single read pass; grid (N/64, B)
// ---------------------------------------------------------------------------
__global__ __launch_bounds__(256) void rmsnorm3(const unsigned short* __restrict__ yb,
                                                const float* __restrict__ colsum,
                                                const float* __restrict__ g,
                                                float* __restrict__ out) {
    const int b = blockIdx.y;
    const int n0 = blockIdx.x * 64;
    const int t = threadIdx.x;
    __shared__ float rinv[64];
    __shared__ float gsh[512];
    if (t < 64) {
        float cs = colsum[b * N + n0 + t];
        rinv[t] = SQRT_D / fmaxf(sqrtf(cs), 1e-12f);
    }
    gsh[t] = g[t];
    gsh[t + 256] = g[t + 256];
    __syncthreads();

    const int cg = (t & 7) * 8;  // col offset within 64
    const int rg = t >> 3;       // row 0..31
    const unsigned short* ybase = yb + (size_t)b * D * N + n0;
    float* obase = out + (size_t)b * D * N + n0;
#pragma unroll 4
    for (int i = 0; i < 16; ++i) {
        int row = rg + i * 32;
        __align__(16) unsigned short v8[8];
        *(uint4*)v8 = *(const uint4*)(ybase + (size_t)row * N + cg);
        float go = gsh[row];
        float o0 = bf2f(v8[0]) * rinv[cg + 0] * go;
        float o1 = bf2f(v8[1]) * rinv[cg + 1] * go;
        float o2 = bf2f(v8[2]) * rinv[cg + 2] * go;
        float o3 = bf2f(v8[3]) * rinv[cg + 3] * go;
        float o4 = bf2f(v8[4]) * rinv[cg + 4] * go;
        float o5 = bf2f(v8[5]) * rinv[cg + 5] * go;
        float o6 = bf2f(v8[6]) * rinv[cg + 6] * go;
        float o7 = bf2f(v8[7]) * rinv[cg + 7] * go;
        *(float4*)(obase + (size_t)row * N + cg) = make_float4(o0, o1, o2, o3);
        *(float4*)(obase + (size_t)row * N + cg + 4) = make_float4(o4, o5, o6, o7);
    }
}

extern "C" void kernel_launch(void* const* d_in, const int* in_sizes, int n_in,
                              void* d_out, int out_size, void* d_ws, size_t ws_size,
                              hipStream_t stream) {
    const float* x = (const float*)d_in[0];
    const float* w_qkv = (const float*)d_in[1];
    const float* w_out = (const float*)d_in[2];
    const float* b_out = (const float*)d_in[3];
    const float* g = (const float*)d_in[4];
    float* out = (float*)d_out;

    // workspace layout
    unsigned short* kvb = (unsigned short*)d_ws;                 // 64 MB
    unsigned short* yb = kvb + (size_t)B * 1024 * N;             // 32 MB
    float* ctx = (float*)(yb + (size_t)B * D * N);               // 1 MB
    float* ksum = ctx + (size_t)B * HEADS * DH * DH;             // 16 KB
    float* colsum = ksum + B * 512;                              // 128 KB
    unsigned short* w2 = (unsigned short*)(colsum + B * N);      // 4 MB
    unsigned short* wqb = w2 + (size_t)B * D * D;                // 1.5 MB
    unsigned short* xT = wqb + (size_t)O3 * KDIM;                // 32 MB
    unsigned short* qT = xT + (size_t)B * N * KDIM;              // 32 MB

    // zero ctx + ksum + colsum (contiguous)
    hipMemsetAsync(ctx, 0,
                   ((size_t)B * HEADS * DH * DH + B * 512 + B * N) * sizeof(float), stream);

    cvt_w<<<dim3(O3 * KDIM / 1024), 256, 0, stream>>>(w_qkv, wqb);
    transpose_x<<<dim3(N / 64, D / 64, B), 256, 0, stream>>>(x, xT);

    gemm_q_sm<<<dim3(N / 128, HID / 128, B), 256, 0, stream>>>(wqb, xT, qT);
    gemm_kv2<<<dim3(N / 128, 8, B), 256, 0, stream>>>(wqb + (size_t)HID * KDIM, xT, kvb, ksum);

    context_mfma2<<<dim3(8, HEADS, B), 256, 0, stream>>>(kvb, ctx);
    fold_wout3<<<dim3(4, HEADS, B), 256, 0, stream>>>(w_out, ctx, ksum, w2);

    gemm_y<<<dim3(N / 128, D / 128, B), 256, 0, stream>>>(w2, qT, b_out, yb, colsum);

    rmsnorm3<<<dim3(N / 64, B), 256, 0, stream>>>(yb, colsum, g, out);
}

// Round 8
// 172.160 us; speedup vs baseline: 1.1703x; 1.1703x over previous
//
#include <hip/hip_runtime.h>
#include <math.h>

#define B 8
#define D 512
#define N 4096
#define HEADS 8
#define DH 64
#define HID 512
#define O3 1536
#define KDIM 512
#define SCALE 0.125f
#define SQRT_D 22.62741699796952f

typedef __attribute__((ext_vector_type(4))) float f32x4;
typedef __attribute__((ext_vector_type(8))) short bf16x8;

static __device__ __forceinline__ unsigned short f2bf(float f) {
    unsigned int u = __float_as_uint(f);
    unsigned int r = (u + 0x7fffu + ((u >> 16) & 1u)) >> 16;
    return (unsigned short)r;
}

static __device__ __forceinline__ float bf2f(unsigned short u) {
    return __uint_as_float((unsigned int)u << 16);
}

static __device__ __forceinline__ void gload_lds16(const void* g, void* l) {
    __builtin_amdgcn_global_load_lds(
        (const __attribute__((address_space(1))) unsigned int*)g,
        (__attribute__((address_space(3))) unsigned int*)l, 16, 0, 0);
}

// ---------------------------------------------------------------------------
// cvt_w: w_qkv fp32 [1536*512] -> bf16
// ---------------------------------------------------------------------------
__global__ __launch_bounds__(256) void cvt_w(const float* __restrict__ w,
                                             unsigned short* __restrict__ wb) {
    int i = (blockIdx.x * 256 + threadIdx.x) * 4;
    float4 v = *(const float4*)(w + i);
    __align__(8) unsigned short o[4] = {f2bf(v.x), f2bf(v.y), f2bf(v.z), f2bf(v.w)};
    *(uint2*)(wb + i) = *(const uint2*)o;
}

// ---------------------------------------------------------------------------
// transpose_x: x fp32 [b][512][4096] -> xT bf16 [b][4096][512]
// ---------------------------------------------------------------------------
__global__ __launch_bounds__(256) void transpose_x(const float* __restrict__ x,
                                                   unsigned short* __restrict__ xT) {
    __shared__ float tile[64][65];
    const int n0 = blockIdx.x * 64, d0 = blockIdx.y * 64, b = blockIdx.z;
    const float* xb = x + (size_t)b * D * N;
    unsigned short* xTb = xT + (size_t)b * N * KDIM;
    const int t = threadIdx.x;
    const int r = t >> 4, c4 = (t & 15) * 4;
#pragma unroll
    for (int i = 0; i < 4; ++i) {
        int row = r + i * 16;
        float4 v = *(const float4*)(xb + (size_t)(d0 + row) * N + n0 + c4);
        tile[row][c4 + 0] = v.x;
        tile[row][c4 + 1] = v.y;
        tile[row][c4 + 2] = v.z;
        tile[row][c4 + 3] = v.w;
    }
    __syncthreads();
#pragma unroll
    for (int pass = 0; pass < 2; ++pass) {
        int orow = (t >> 3) + pass * 32;
        int oc = (t & 7) * 8;
        __align__(16) unsigned short o[8];
#pragma unroll
        for (int e = 0; e < 8; ++e) o[e] = f2bf(tile[oc + e][orow]);
        *(uint4*)(xTb + (size_t)(n0 + orow) * KDIM + d0 + oc) = *(const uint4*)o;
    }
}

// ---------------------------------------------------------------------------
// shared GEMM core: 128x128 tile, BK=64, 4 waves, mfma_f32_16x16x32_bf16
// ---------------------------------------------------------------------------
#define GEMM_CORE(A_PTR, BT_PTR, ACC)                                              \
    __shared__ __align__(16) unsigned short As[128 * 64];                          \
    __shared__ __align__(16) unsigned short Bs[128 * 64];                          \
    const int t = threadIdx.x;                                                     \
    const int lane = t & 63;                                                       \
    const int wid = t >> 6;                                                        \
    const int wm = wid >> 1, wn = wid & 1;                                         \
    int prow[4], coff[4];                                                          \
    _Pragma("unroll") for (int i = 0; i < 4; ++i) {                                \
        int p = i * 4096 + t * 16;                                                 \
        int pr = p >> 7;                                                           \
        int pc = (p >> 4) & 7;                                                     \
        prow[i] = pr;                                                              \
        coff[i] = (pc ^ (pr & 7)) * 8;                                             \
    }                                                                              \
    int aoff[4][2], boff[4][2];                                                    \
    _Pragma("unroll") for (int m = 0; m < 4; ++m) {                                \
        int arow = wm * 64 + m * 16 + (lane & 15);                                 \
        int brow = wn * 64 + m * 16 + (lane & 15);                                 \
        _Pragma("unroll") for (int s = 0; s < 2; ++s) {                            \
            int chunk = s * 4 + (lane >> 4);                                       \
            aoff[m][s] = arow * 128 + ((chunk ^ (arow & 7)) << 4);                 \
            boff[m][s] = brow * 128 + ((chunk ^ (brow & 7)) << 4);                 \
        }                                                                          \
    }                                                                              \
    f32x4 ACC[4][4] = {};                                                          \
    for (int k0 = 0; k0 < KDIM; k0 += 64) {                                        \
        _Pragma("unroll") for (int i = 0; i < 4; ++i)                              \
            gload_lds16(A_PTR + (size_t)(row0 + prow[i]) * KDIM + k0 + coff[i],    \
                        (char*)As + i * 4096 + t * 16);                            \
        _Pragma("unroll") for (int i = 0; i < 4; ++i)                              \
            gload_lds16(BT_PTR + (size_t)(col0 + prow[i]) * KDIM + k0 + coff[i],   \
                        (char*)Bs + i * 4096 + t * 16);                            \
        __syncthreads();                                                           \
        bf16x8 af[4][2], bfr[4][2];                                                \
        _Pragma("unroll") for (int m = 0; m < 4; ++m)                              \
            _Pragma("unroll") for (int s = 0; s < 2; ++s) {                        \
                af[m][s] = *(const bf16x8*)((const char*)As + aoff[m][s]);         \
                bfr[m][s] = *(const bf16x8*)((const char*)Bs + boff[m][s]);        \
            }                                                                      \
        _Pragma("unroll") for (int s = 0; s < 2; ++s)                              \
            _Pragma("unroll") for (int m = 0; m < 4; ++m)                          \
                _Pragma("unroll") for (int n = 0; n < 4; ++n)                      \
                    ACC[m][n] = __builtin_amdgcn_mfma_f32_16x16x32_bf16(           \
                        af[m][s], bfr[n][s], ACC[m][n], 0, 0, 0);                  \
        __syncthreads();                                                           \
    }

// ---------------------------------------------------------------------------
// gemm_kv: k,v = w_qkv[512:1536] @ x -> bf16 kvb [b][1024][N]  (R6 version)
// ---------------------------------------------------------------------------
__global__ __launch_bounds__(256) void gemm_kv(const unsigned short* __restrict__ Aw,
                                               const unsigned short* __restrict__ BTall,
                                               unsigned short* __restrict__ kvall) {
    const int b = blockIdx.z;
    const unsigned short* A = Aw;
    const unsigned short* BT = BTall + (size_t)b * N * KDIM;
    unsigned short* C = kvall + (size_t)b * 1024 * N;
    const int row0 = blockIdx.y * 128;
    const int col0 = blockIdx.x * 128;
    GEMM_CORE(A, BT, acc)
#pragma unroll
    for (int m = 0; m < 4; ++m) {
        int row_b = row0 + wm * 64 + m * 16 + (lane >> 4) * 4;
#pragma unroll
        for (int n = 0; n < 4; ++n) {
            int col = col0 + wn * 64 + n * 16 + (lane & 15);
#pragma unroll
            for (int r = 0; r < 4; ++r)
                C[(size_t)(row_b + r) * N + col] = f2bf(acc[m][n][r]);
        }
    }
}

// ---------------------------------------------------------------------------
// gemm_q_sm: q GEMM + fused softmax over d per head -> qT bf16 [b][n][512]
// ---------------------------------------------------------------------------
__global__ __launch_bounds__(256) void gemm_q_sm(const unsigned short* __restrict__ Aw,
                                                 const unsigned short* __restrict__ BTall,
                                                 unsigned short* __restrict__ qT) {
    const int b = blockIdx.z;
    const unsigned short* A = Aw;
    const unsigned short* BT = BTall + (size_t)b * N * KDIM;
    const int row0 = blockIdx.y * 128;
    const int col0 = blockIdx.x * 128;
    GEMM_CORE(A, BT, acc)
    const int h = blockIdx.y * 2 + wm;
    const int g = lane >> 4;
#pragma unroll
    for (int nf = 0; nf < 4; ++nf) {
        float mx = -1e30f;
#pragma unroll
        for (int m = 0; m < 4; ++m)
#pragma unroll
            for (int r = 0; r < 4; ++r) mx = fmaxf(mx, acc[m][nf][r]);
        mx = fmaxf(mx, __shfl_xor(mx, 16));
        mx = fmaxf(mx, __shfl_xor(mx, 32));
        float e[16];
        float s = 0.f;
#pragma unroll
        for (int m = 0; m < 4; ++m)
#pragma unroll
            for (int r = 0; r < 4; ++r) {
                e[m * 4 + r] = __expf(acc[m][nf][r] - mx);
                s += e[m * 4 + r];
            }
        s += __shfl_xor(s, 16);
        s += __shfl_xor(s, 32);
        float rs = SCALE / s;
        int n = col0 + wn * 64 + nf * 16 + (lane & 15);
        unsigned short* dst = qT + ((size_t)b * N + n) * KDIM + h * 64 + g * 4;
#pragma unroll
        for (int m = 0; m < 4; ++m) {
            __align__(8) unsigned short o4[4] = {f2bf(e[m * 4 + 0] * rs), f2bf(e[m * 4 + 1] * rs),
                                                 f2bf(e[m * 4 + 2] * rs), f2bf(e[m * 4 + 3] * rs)};
            *(uint2*)(dst + m * 16) = *(const uint2*)o4;
        }
    }
}

// ---------------------------------------------------------------------------
// context_mfma3: per (b,h,chunk): ctx[d][e] += sum_n exp(k[d,n]) * v[e,n]
// plus ksum[d] += sum_n exp(k[d,n]) via MFMA against a ones vector.
// k reg-staged with exp applied (swizzled ds_write); v via global_load_lds.
// No max subtraction: |k| <= ~3 so exp(k) <= ~20, bf16-safe.
// ---------------------------------------------------------------------------
__global__ __launch_bounds__(256) void context_mfma3(const unsigned short* __restrict__ kvb,
                                                     float* __restrict__ ctx,
                                                     float* __restrict__ ksum) {
    const int ch = blockIdx.x, h = blockIdx.y, b = blockIdx.z;
    const int K0 = ch * 512;
    const unsigned short* kbase = kvb + ((size_t)b * 1024 + h * DH) * (size_t)N + K0;
    const unsigned short* vbase = kvb + ((size_t)b * 1024 + 512 + h * DH) * (size_t)N + K0;

    __shared__ __align__(16) unsigned short Ks[64 * 64];
    __shared__ __align__(16) unsigned short Vs[64 * 64];

    const int t = threadIdx.x;
    const int lane = t & 63;
    const int wv = t >> 6;

    // k staging: thread t handles row kr, cols kc..kc+15 (two 16B chunks)
    const int kr = t >> 2;
    const int kc = (t & 3) * 16;
    const int kchunk0 = kc >> 3;  // 0,2,4,6
    const int kdst0 = kr * 128 + (((kchunk0 + 0) ^ (kr & 7)) << 4);
    const int kdst1 = kr * 128 + (((kchunk0 + 1) ^ (kr & 7)) << 4);

    // v staging geometry (gload_lds, inverse-swizzled source)
    int vrow[2], vcoff[2];
#pragma unroll
    for (int i = 0; i < 2; ++i) {
        int p = i * 4096 + t * 16;
        int pr = p >> 7;
        int pc = (p >> 4) & 7;
        vrow[i] = pr;
        vcoff[i] = (pc ^ (pr & 7)) * 8;
    }

    // fragment read offsets
    const int ar = wv * 16 + (lane & 15);
    int aoff[2], boff[4][2];
#pragma unroll
    for (int s = 0; s < 2; ++s) {
        int chunk = s * 4 + (lane >> 4);
        aoff[s] = ar * 128 + ((chunk ^ (ar & 7)) << 4);
#pragma unroll
        for (int nf = 0; nf < 4; ++nf) {
            int br = nf * 16 + (lane & 15);
            boff[nf][s] = br * 128 + ((chunk ^ (br & 7)) << 4);
        }
    }

    // ones vector (bf16 1.0 = 0x3F80) for row-sum MFMA
    bf16x8 ones;
#pragma unroll
    for (int j = 0; j < 8; ++j) ones[j] = (short)0x3F80;

    f32x4 acc[4] = {};
    f32x4 accs = {};

    for (int k0 = 0; k0 < 512; k0 += 64) {
        // stage v (async)
#pragma unroll
        for (int i = 0; i < 2; ++i)
            gload_lds16(vbase + (size_t)vrow[i] * N + k0 + vcoff[i],
                        (char*)Vs + i * 4096 + t * 16);
        // stage k with exp
        __align__(16) unsigned short raw[16];
        *(uint4*)raw = *(const uint4*)(kbase + (size_t)kr * N + k0 + kc);
        *(uint4*)(raw + 8) = *(const uint4*)(kbase + (size_t)kr * N + k0 + kc + 8);
        __align__(16) unsigned short o[16];
#pragma unroll
        for (int j = 0; j < 16; ++j) o[j] = f2bf(__expf(bf2f(raw[j])));
        *(uint4*)((char*)Ks + kdst0) = *(const uint4*)o;
        *(uint4*)((char*)Ks + kdst1) = *(const uint4*)(o + 8);
        __syncthreads();

        bf16x8 av[2], bv[4][2];
#pragma unroll
        for (int s = 0; s < 2; ++s) {
            av[s] = *(const bf16x8*)((const char*)Ks + aoff[s]);
#pragma unroll
            for (int nf = 0; nf < 4; ++nf)
                bv[nf][s] = *(const bf16x8*)((const char*)Vs + boff[nf][s]);
        }
#pragma unroll
        for (int s = 0; s < 2; ++s) {
#pragma unroll
            for (int nf = 0; nf < 4; ++nf)
                acc[nf] = __builtin_amdgcn_mfma_f32_16x16x32_bf16(av[s], bv[nf][s], acc[nf], 0, 0, 0);
            accs = __builtin_amdgcn_mfma_f32_16x16x32_bf16(av[s], ones, accs, 0, 0, 0);
        }
        __syncthreads();
    }

    float* cbase = ctx + ((size_t)(b * HEADS + h)) * DH * DH;
    const int drow = wv * 16 + (lane >> 4) * 4;
#pragma unroll
    for (int nf = 0; nf < 4; ++nf) {
        int e = nf * 16 + (lane & 15);
#pragma unroll
        for (int rr = 0; rr < 4; ++rr)
            atomicAdd(&cbase[(drow + rr) * DH + e], acc[nf][rr]);
    }
    // row-sum: every lane holds the same sum replicated across cols; col 0 lanes commit
    if ((lane & 15) == 0) {
#pragma unroll
        for (int rr = 0; rr < 4; ++rr)
            atomicAdd(&ksum[b * 512 + h * DH + drow + rr], accs[rr]);
    }
}

// ---------------------------------------------------------------------------
// fold_wout3: per (b,h): W2[o][d] = sum_e w_out[o][h*64+e] * ctx[b,h,d,e]/ksum[d]
// ---------------------------------------------------------------------------
__global__ __launch_bounds__(256) void fold_wout3(const float* __restrict__ w_out,
                                                  const float* __restrict__ ctx,
                                                  const float* __restrict__ ksum,
                                                  unsigned short* __restrict__ w2) {
    const int ot = blockIdx.x, h = blockIdx.y, b = blockIdx.z;
    __shared__ __align__(16) unsigned short As[128 * 64];
    __shared__ __align__(16) unsigned short Bs[64 * 64];
    const int t = threadIdx.x;
    const int lane = t & 63;
    const int wv = t >> 6;

#pragma unroll
    for (int i = 0; i < 8; ++i) {
        int lin = t + i * 256;
        int r = lin >> 4;
        int c4 = (lin & 15) * 4;
        float4 v = *(const float4*)(w_out + (size_t)(ot * 128 + r) * HID + h * 64 + c4);
        __align__(8) unsigned short o4[4] = {f2bf(v.x), f2bf(v.y), f2bf(v.z), f2bf(v.w)};
        int chunk = c4 >> 3;
        int off = (c4 & 7) * 2;
        *(uint2*)((char*)As + r * 128 + ((chunk ^ (r & 7)) << 4) + off) = *(const uint2*)o4;
    }
    const float* cb = ctx + ((size_t)(b * HEADS + h)) * DH * DH;
    const float* ks = ksum + b * 512 + h * 64;
#pragma unroll
    for (int i = 0; i < 4; ++i) {
        int lin = t + i * 256;
        int r = lin >> 4;
        int c4 = (lin & 15) * 4;
        float inv = 1.0f / ks[r];
        float4 v = *(const float4*)(cb + (size_t)r * DH + c4);
        __align__(8) unsigned short o4[4] = {f2bf(v.x * inv), f2bf(v.y * inv),
                                             f2bf(v.z * inv), f2bf(v.w * inv)};
        int chunk = c4 >> 3;
        int off = (c4 & 7) * 2;
        *(uint2*)((char*)Bs + r * 128 + ((chunk ^ (r & 7)) << 4) + off) = *(const uint2*)o4;
    }
    __syncthreads();

    f32x4 acc[2][4] = {};
#pragma unroll
    for (int s = 0; s < 2; ++s) {
        int chunk = s * 4 + (lane >> 4);
        bf16x8 bf[4];
#pragma unroll
        for (int nf = 0; nf < 4; ++nf) {
            int brow = nf * 16 + (lane & 15);
            bf[nf] = *(const bf16x8*)((const char*)Bs + brow * 128 + ((chunk ^ (brow & 7)) << 4));
        }
#pragma unroll
        for (int mm = 0; mm < 2; ++mm) {
            int arow = (wv * 2 + mm) * 16 + (lane & 15);
            bf16x8 a = *(const bf16x8*)((const char*)As + arow * 128 + ((chunk ^ (arow & 7)) << 4));
#pragma unroll
            for (int nf = 0; nf < 4; ++nf)
                acc[mm][nf] = __builtin_amdgcn_mfma_f32_16x16x32_bf16(a, bf[nf], acc[mm][nf], 0, 0, 0);
        }
    }

#pragma unroll
    for (int mm = 0; mm < 2; ++mm) {
        int o_base = ot * 128 + (wv * 2 + mm) * 16 + (lane >> 4) * 4;
#pragma unroll
        for (int nf = 0; nf < 4; ++nf) {
            int d = nf * 16 + (lane & 15);
#pragma unroll
            for (int rr = 0; rr < 4; ++rr)
                w2[((size_t)(b * D) + o_base + rr) * D + h * 64 + d] = f2bf(acc[mm][nf][rr]);
        }
    }
}

// ---------------------------------------------------------------------------
// gemm_y: y = W2[b] @ qT + bias -> fp32 out, plus per-column sum(y^2) atomics
// ---------------------------------------------------------------------------
__global__ __launch_bounds__(256) void gemm_y(const unsigned short* __restrict__ w2all,
                                              const unsigned short* __restrict__ qTall,
                                              const float* __restrict__ bias,
                                              float* __restrict__ yall,
                                              float* __restrict__ colsum) {
    const int b = blockIdx.z;
    const unsigned short* A = w2all + (size_t)b * D * D;
    const unsigned short* BT = qTall + (size_t)b * N * KDIM;
    float* y = yall + (size_t)b * D * N;
    const int row0 = blockIdx.y * 128;
    const int col0 = blockIdx.x * 128;
    GEMM_CORE(A, BT, acc)

    float csum[4] = {0.f, 0.f, 0.f, 0.f};
#pragma unroll
    for (int m = 0; m < 4; ++m) {
        int row_b = row0 + wm * 64 + m * 16 + (lane >> 4) * 4;
#pragma unroll
        for (int r = 0; r < 4; ++r) {
            float bv = bias[row_b + r];
#pragma unroll
            for (int n = 0; n < 4; ++n) {
                int col = col0 + wn * 64 + n * 16 + (lane & 15);
                float e = acc[m][n][r] + bv;
                y[(size_t)(row_b + r) * N + col] = e;
                csum[n] += e * e;
            }
        }
    }
#pragma unroll
    for (int n = 0; n < 4; ++n) {
        csum[n] += __shfl_xor(csum[n], 16);
        csum[n] += __shfl_xor(csum[n], 32);
    }
    if (lane < 16) {
#pragma unroll
        for (int n = 0; n < 4; ++n) {
            int col = col0 + wn * 64 + n * 16 + lane;
            atomicAdd(&colsum[b * N + col], csum[n]);
        }
    }
}

// ---------------------------------------------------------------------------
// colprep: colsum -> SQRT_D / max(sqrt(colsum), eps)   (B*N elements)
// ---------------------------------------------------------------------------
__global__ __launch_bounds__(256) void colprep(float* __restrict__ cs) {
    int i = blockIdx.x * 256 + threadIdx.x;
    float v = cs[i];
    cs[i] = SQRT_D / fmaxf(sqrtf(v), 1e-12f);
}

// ---------------------------------------------------------------------------
// rmsnorm4: in-place elementwise scale: y *= rinv[b,n] * g[o]
// ---------------------------------------------------------------------------
__global__ __launch_bounds__(256) void rmsnorm4(float4* __restrict__ y,
                                                const float4* __restrict__ rinv,
                                                const float* __restrict__ g) {
    const size_t total = (size_t)B * D * N / 4;
    for (size_t i = blockIdx.x * 256 + threadIdx.x; i < total; i += 524288) {
        int b = (int)(i >> 19);       // / (D*N/4) = 2^19
        int rem = (int)(i & 524287);
        int o = rem >> 10;            // / (N/4)
        int n4 = rem & 1023;
        float4 v = y[i];
        float4 rv = rinv[b * 1024 + n4];
        float go = g[o];
        v.x *= rv.x * go;
        v.y *= rv.y * go;
        v.z *= rv.z * go;
        v.w *= rv.w * go;
        y[i] = v;
    }
}

extern "C" void kernel_launch(void* const* d_in, const int* in_sizes, int n_in,
                              void* d_out, int out_size, void* d_ws, size_t ws_size,
                              hipStream_t stream) {
    const float* x = (const float*)d_in[0];
    const float* w_qkv = (const float*)d_in[1];
    const float* w_out = (const float*)d_in[2];
    const float* b_out = (const float*)d_in[3];
    const float* g = (const float*)d_in[4];
    float* out = (float*)d_out;

    // workspace layout
    unsigned short* kvb = (unsigned short*)d_ws;                 // 64 MB
    float* ctx = (float*)(kvb + (size_t)B * 1024 * N);           // 1 MB
    float* ksum = ctx + (size_t)B * HEADS * DH * DH;             // 16 KB
    float* colsum = ksum + B * 512;                              // 128 KB
    unsigned short* w2 = (unsigned short*)(colsum + B * N);      // 4 MB
    unsigned short* wqb = w2 + (size_t)B * D * D;                // 1.5 MB
    unsigned short* xT = wqb + (size_t)O3 * KDIM;                // 32 MB
    unsigned short* qT = xT + (size_t)B * N * KDIM;              // 32 MB

    // zero ctx + ksum + colsum (contiguous)
    hipMemsetAsync(ctx, 0,
                   ((size_t)B * HEADS * DH * DH + B * 512 + B * N) * sizeof(float), stream);

    cvt_w<<<dim3(O3 * KDIM / 1024), 256, 0, stream>>>(w_qkv, wqb);
    transpose_x<<<dim3(N / 64, D / 64, B), 256, 0, stream>>>(x, xT);

    gemm_q_sm<<<dim3(N / 128, HID / 128, B), 256, 0, stream>>>(wqb, xT, qT);
    gemm_kv<<<dim3(N / 128, 8, B), 256, 0, stream>>>(wqb + (size_t)HID * KDIM, xT, kvb);

    context_mfma3<<<dim3(8, HEADS, B), 256, 0, stream>>>(kvb, ctx, ksum);
    fold_wout3<<<dim3(4, HEADS, B), 256, 0, stream>>>(w_out, ctx, ksum, w2);

    gemm_y<<<dim3(N / 128, D / 128, B), 256, 0, stream>>>(w2, qT, b_out, out, colsum);

    colprep<<<dim3(B * N / 256), 256, 0, stream>>>(colsum);
    rmsnorm4<<<dim3(2048), 256, 0, stream>>>((float4*)out, (const float4*)colsum, g);
}

// Round 9
// 169.181 us; speedup vs baseline: 1.1910x; 1.0176x over previous
//
#include <hip/hip_runtime.h>
#include <math.h>

#define B 8
#define D 512
#define N 4096
#define HEADS 8
#define DH 64
#define HID 512
#define O3 1536
#define KDIM 512
#define SCALE 0.125f
#define SQRT_D 22.62741699796952f

typedef __attribute__((ext_vector_type(4))) float f32x4;
typedef __attribute__((ext_vector_type(8))) short bf16x8;

static __device__ __forceinline__ unsigned short f2bf(float f) {
    unsigned int u = __float_as_uint(f);
    unsigned int r = (u + 0x7fffu + ((u >> 16) & 1u)) >> 16;
    return (unsigned short)r;
}

static __device__ __forceinline__ float bf2f(unsigned short u) {
    return __uint_as_float((unsigned int)u << 16);
}

static __device__ __forceinline__ void gload_lds16(const void* g, void* l) {
    __builtin_amdgcn_global_load_lds(
        (const __attribute__((address_space(1))) unsigned int*)g,
        (__attribute__((address_space(3))) unsigned int*)l, 16, 0, 0);
}

// ---------------------------------------------------------------------------
// cvt_w: w_qkv fp32 [1536*512] -> bf16
// ---------------------------------------------------------------------------
__global__ __launch_bounds__(256) void cvt_w(const float* __restrict__ w,
                                             unsigned short* __restrict__ wb) {
    int i = (blockIdx.x * 256 + threadIdx.x) * 4;
    float4 v = *(const float4*)(w + i);
    __align__(8) unsigned short o[4] = {f2bf(v.x), f2bf(v.y), f2bf(v.z), f2bf(v.w)};
    *(uint2*)(wb + i) = *(const uint2*)o;
}

// ---------------------------------------------------------------------------
// transpose_x: x fp32 [b][512][4096] -> xT bf16 [b][4096][512]
// ---------------------------------------------------------------------------
__global__ __launch_bounds__(256) void transpose_x(const float* __restrict__ x,
                                                   unsigned short* __restrict__ xT) {
    __shared__ float tile[64][65];
    const int n0 = blockIdx.x * 64, d0 = blockIdx.y * 64, b = blockIdx.z;
    const float* xb = x + (size_t)b * D * N;
    unsigned short* xTb = xT + (size_t)b * N * KDIM;
    const int t = threadIdx.x;
    const int r = t >> 4, c4 = (t & 15) * 4;
#pragma unroll
    for (int i = 0; i < 4; ++i) {
        int row = r + i * 16;
        float4 v = *(const float4*)(xb + (size_t)(d0 + row) * N + n0 + c4);
        tile[row][c4 + 0] = v.x;
        tile[row][c4 + 1] = v.y;
        tile[row][c4 + 2] = v.z;
        tile[row][c4 + 3] = v.w;
    }
    __syncthreads();
#pragma unroll
    for (int pass = 0; pass < 2; ++pass) {
        int orow = (t >> 3) + pass * 32;
        int oc = (t & 7) * 8;
        __align__(16) unsigned short o[8];
#pragma unroll
        for (int e = 0; e < 8; ++e) o[e] = f2bf(tile[oc + e][orow]);
        *(uint4*)(xTb + (size_t)(n0 + orow) * KDIM + d0 + oc) = *(const uint4*)o;
    }
}

// ---------------------------------------------------------------------------
// double-buffered GEMM core: 128x128 tile, BK=64, 4 waves, one barrier/K-tile.
// Stage of tile t+1 is issued BEFORE compute of tile t (T3 minimum 2-phase).
// Buffer parity: iteration kt reads buf[kt&1] (staged at kt-1), stages
// buf[(kt+1)&1] whose previous readers were sealed by the kt-1 barrier.
// ---------------------------------------------------------------------------
#define STAGE_AB(A_PTR, BT_PTR, BUFOFF, KOFF)                                      \
    _Pragma("unroll") for (int i = 0; i < 4; ++i)                                  \
        gload_lds16(A_PTR + (size_t)(row0 + prow[i]) * KDIM + (KOFF) + coff[i],    \
                    (char*)As + (BUFOFF) + i * 4096 + t * 16);                     \
    _Pragma("unroll") for (int i = 0; i < 4; ++i)                                  \
        gload_lds16(BT_PTR + (size_t)(col0 + prow[i]) * KDIM + (KOFF) + coff[i],   \
                    (char*)Bs + (BUFOFF) + i * 4096 + t * 16);

#define GEMM_CORE_DB(A_PTR, BT_PTR, ACC)                                           \
    __shared__ __align__(16) unsigned short As[2 * 128 * 64];                      \
    __shared__ __align__(16) unsigned short Bs[2 * 128 * 64];                      \
    const int t = threadIdx.x;                                                     \
    const int lane = t & 63;                                                       \
    const int wid = t >> 6;                                                        \
    const int wm = wid >> 1, wn = wid & 1;                                         \
    int prow[4], coff[4];                                                          \
    _Pragma("unroll") for (int i = 0; i < 4; ++i) {                                \
        int p = i * 4096 + t * 16;                                                 \
        int pr = p >> 7;                                                           \
        int pc = (p >> 4) & 7;                                                     \
        prow[i] = pr;                                                              \
        coff[i] = (pc ^ (pr & 7)) * 8;                                             \
    }                                                                              \
    int aoff[4][2], boff[4][2];                                                    \
    _Pragma("unroll") for (int m = 0; m < 4; ++m) {                                \
        int arow = wm * 64 + m * 16 + (lane & 15);                                 \
        int brow = wn * 64 + m * 16 + (lane & 15);                                 \
        _Pragma("unroll") for (int s = 0; s < 2; ++s) {                            \
            int chunk = s * 4 + (lane >> 4);                                       \
            aoff[m][s] = arow * 128 + ((chunk ^ (arow & 7)) << 4);                 \
            boff[m][s] = brow * 128 + ((chunk ^ (brow & 7)) << 4);                 \
        }                                                                          \
    }                                                                              \
    f32x4 ACC[4][4] = {};                                                          \
    { STAGE_AB(A_PTR, BT_PTR, 0, 0) }                                              \
    __syncthreads();                                                               \
    for (int kt = 0; kt < 8; ++kt) {                                               \
        if (kt < 7) {                                                              \
            STAGE_AB(A_PTR, BT_PTR, ((kt + 1) & 1) * 16384, (kt + 1) * 64)         \
        }                                                                          \
        const int bo = (kt & 1) * 16384;                                           \
        bf16x8 af[4][2], bfr[4][2];                                                \
        _Pragma("unroll") for (int m = 0; m < 4; ++m)                              \
            _Pragma("unroll") for (int s = 0; s < 2; ++s) {                        \
                af[m][s] = *(const bf16x8*)((const char*)As + bo + aoff[m][s]);    \
                bfr[m][s] = *(const bf16x8*)((const char*)Bs + bo + boff[m][s]);   \
            }                                                                      \
        _Pragma("unroll") for (int s = 0; s < 2; ++s)                              \
            _Pragma("unroll") for (int m = 0; m < 4; ++m)                          \
                _Pragma("unroll") for (int n = 0; n < 4; ++n)                      \
                    ACC[m][n] = __builtin_amdgcn_mfma_f32_16x16x32_bf16(           \
                        af[m][s], bfr[n][s], ACC[m][n], 0, 0, 0);                  \
        __syncthreads();                                                           \
    }

// ---------------------------------------------------------------------------
// gemm_qkv: fused qkv = w_qkv @ x.
// blockIdx.y < 4: q rows, softmax over d per head -> qT bf16 [b][n][512]
// blockIdx.y >= 4: k,v rows -> bf16 kvb [b][1024][N]
// ---------------------------------------------------------------------------
__global__ __launch_bounds__(256) void gemm_qkv(const unsigned short* __restrict__ Aw,
                                                const unsigned short* __restrict__ BTall,
                                                unsigned short* __restrict__ qT,
                                                unsigned short* __restrict__ kvall) {
    const int b = blockIdx.z;
    const unsigned short* A = Aw;
    const unsigned short* BT = BTall + (size_t)b * N * KDIM;
    const int row0 = blockIdx.y * 128;
    const int col0 = blockIdx.x * 128;
    GEMM_CORE_DB(A, BT, acc)

    if (blockIdx.y < 4) {
        // q path: softmax over the wave's head (64 rows) per column
        const int h = blockIdx.y * 2 + wm;
        const int g = lane >> 4;
#pragma unroll
        for (int nf = 0; nf < 4; ++nf) {
            float mx = -1e30f;
#pragma unroll
            for (int m = 0; m < 4; ++m)
#pragma unroll
                for (int r = 0; r < 4; ++r) mx = fmaxf(mx, acc[m][nf][r]);
            mx = fmaxf(mx, __shfl_xor(mx, 16));
            mx = fmaxf(mx, __shfl_xor(mx, 32));
            float e[16];
            float s = 0.f;
#pragma unroll
            for (int m = 0; m < 4; ++m)
#pragma unroll
                for (int r = 0; r < 4; ++r) {
                    e[m * 4 + r] = __expf(acc[m][nf][r] - mx);
                    s += e[m * 4 + r];
                }
            s += __shfl_xor(s, 16);
            s += __shfl_xor(s, 32);
            float rs = SCALE / s;
            int n = col0 + wn * 64 + nf * 16 + (lane & 15);
            unsigned short* dst = qT + ((size_t)b * N + n) * KDIM + h * 64 + g * 4;
#pragma unroll
            for (int m = 0; m < 4; ++m) {
                __align__(8) unsigned short o4[4] = {
                    f2bf(e[m * 4 + 0] * rs), f2bf(e[m * 4 + 1] * rs),
                    f2bf(e[m * 4 + 2] * rs), f2bf(e[m * 4 + 3] * rs)};
                *(uint2*)(dst + m * 16) = *(const uint2*)o4;
            }
        }
    } else {
        unsigned short* C = kvall + (size_t)b * 1024 * N;
        const int rbase = row0 - 512;
#pragma unroll
        for (int m = 0; m < 4; ++m) {
            int row_b = rbase + wm * 64 + m * 16 + (lane >> 4) * 4;
#pragma unroll
            for (int n = 0; n < 4; ++n) {
                int col = col0 + wn * 64 + n * 16 + (lane & 15);
#pragma unroll
                for (int r = 0; r < 4; ++r)
                    C[(size_t)(row_b + r) * N + col] = f2bf(acc[m][n][r]);
            }
        }
    }
}

// ---------------------------------------------------------------------------
// context_mfma3: per (b,h,chunk): ctx[d][e] += sum_n exp(k[d,n]) * v[e,n]
// plus ksum[d] += sum_n exp(k[d,n]) via MFMA against a ones vector.
// ---------------------------------------------------------------------------
__global__ __launch_bounds__(256) void context_mfma3(const unsigned short* __restrict__ kvb,
                                                     float* __restrict__ ctx,
                                                     float* __restrict__ ksum) {
    const int ch = blockIdx.x, h = blockIdx.y, b = blockIdx.z;
    const int K0 = ch * 512;
    const unsigned short* kbase = kvb + ((size_t)b * 1024 + h * DH) * (size_t)N + K0;
    const unsigned short* vbase = kvb + ((size_t)b * 1024 + 512 + h * DH) * (size_t)N + K0;

    __shared__ __align__(16) unsigned short Ks[64 * 64];
    __shared__ __align__(16) unsigned short Vs[64 * 64];

    const int t = threadIdx.x;
    const int lane = t & 63;
    const int wv = t >> 6;

    const int kr = t >> 2;
    const int kc = (t & 3) * 16;
    const int kchunk0 = kc >> 3;
    const int kdst0 = kr * 128 + (((kchunk0 + 0) ^ (kr & 7)) << 4);
    const int kdst1 = kr * 128 + (((kchunk0 + 1) ^ (kr & 7)) << 4);

    int vrow[2], vcoff[2];
#pragma unroll
    for (int i = 0; i < 2; ++i) {
        int p = i * 4096 + t * 16;
        int pr = p >> 7;
        int pc = (p >> 4) & 7;
        vrow[i] = pr;
        vcoff[i] = (pc ^ (pr & 7)) * 8;
    }

    const int ar = wv * 16 + (lane & 15);
    int aoff[2], boff[4][2];
#pragma unroll
    for (int s = 0; s < 2; ++s) {
        int chunk = s * 4 + (lane >> 4);
        aoff[s] = ar * 128 + ((chunk ^ (ar & 7)) << 4);
#pragma unroll
        for (int nf = 0; nf < 4; ++nf) {
            int br = nf * 16 + (lane & 15);
            boff[nf][s] = br * 128 + ((chunk ^ (br & 7)) << 4);
        }
    }

    bf16x8 ones;
#pragma unroll
    for (int j = 0; j < 8; ++j) ones[j] = (short)0x3F80;

    f32x4 acc[4] = {};
    f32x4 accs = {};

    for (int k0 = 0; k0 < 512; k0 += 64) {
#pragma unroll
        for (int i = 0; i < 2; ++i)
            gload_lds16(vbase + (size_t)vrow[i] * N + k0 + vcoff[i],
                        (char*)Vs + i * 4096 + t * 16);
        __align__(16) unsigned short raw[16];
        *(uint4*)raw = *(const uint4*)(kbase + (size_t)kr * N + k0 + kc);
        *(uint4*)(raw + 8) = *(const uint4*)(kbase + (size_t)kr * N + k0 + kc + 8);
        __align__(16) unsigned short o[16];
#pragma unroll
        for (int j = 0; j < 16; ++j) o[j] = f2bf(__expf(bf2f(raw[j])));
        *(uint4*)((char*)Ks + kdst0) = *(const uint4*)o;
        *(uint4*)((char*)Ks + kdst1) = *(const uint4*)(o + 8);
        __syncthreads();

        bf16x8 av[2], bv[4][2];
#pragma unroll
        for (int s = 0; s < 2; ++s) {
            av[s] = *(const bf16x8*)((const char*)Ks + aoff[s]);
#pragma unroll
            for (int nf = 0; nf < 4; ++nf)
                bv[nf][s] = *(const bf16x8*)((const char*)Vs + boff[nf][s]);
        }
#pragma unroll
        for (int s = 0; s < 2; ++s) {
#pragma unroll
            for (int nf = 0; nf < 4; ++nf)
                acc[nf] = __builtin_amdgcn_mfma_f32_16x16x32_bf16(av[s], bv[nf][s], acc[nf], 0, 0, 0);
            accs = __builtin_amdgcn_mfma_f32_16x16x32_bf16(av[s], ones, accs, 0, 0, 0);
        }
        __syncthreads();
    }

    float* cbase = ctx + ((size_t)(b * HEADS + h)) * DH * DH;
    const int drow = wv * 16 + (lane >> 4) * 4;
#pragma unroll
    for (int nf = 0; nf < 4; ++nf) {
        int e = nf * 16 + (lane & 15);
#pragma unroll
        for (int rr = 0; rr < 4; ++rr)
            atomicAdd(&cbase[(drow + rr) * DH + e], acc[nf][rr]);
    }
    if ((lane & 15) == 0) {
#pragma unroll
        for (int rr = 0; rr < 4; ++rr)
            atomicAdd(&ksum[b * 512 + h * DH + drow + rr], accs[rr]);
    }
}

// ---------------------------------------------------------------------------
// fold_wout3: per (b,h): W2[o][d] = sum_e w_out[o][h*64+e] * ctx[b,h,d,e]/ksum[d]
// ---------------------------------------------------------------------------
__global__ __launch_bounds__(256) void fold_wout3(const float* __restrict__ w_out,
                                                  const float* __restrict__ ctx,
                                                  const float* __restrict__ ksum,
                                                  unsigned short* __restrict__ w2) {
    const int ot = blockIdx.x, h = blockIdx.y, b = blockIdx.z;
    __shared__ __align__(16) unsigned short As[128 * 64];
    __shared__ __align__(16) unsigned short Bs[64 * 64];
    const int t = threadIdx.x;
    const int lane = t & 63;
    const int wv = t >> 6;

#pragma unroll
    for (int i = 0; i < 8; ++i) {
        int lin = t + i * 256;
        int r = lin >> 4;
        int c4 = (lin & 15) * 4;
        float4 v = *(const float4*)(w_out + (size_t)(ot * 128 + r) * HID + h * 64 + c4);
        __align__(8) unsigned short o4[4] = {f2bf(v.x), f2bf(v.y), f2bf(v.z), f2bf(v.w)};
        int chunk = c4 >> 3;
        int off = (c4 & 7) * 2;
        *(uint2*)((char*)As + r * 128 + ((chunk ^ (r & 7)) << 4) + off) = *(const uint2*)o4;
    }
    const float* cb = ctx + ((size_t)(b * HEADS + h)) * DH * DH;
    const float* ks = ksum + b * 512 + h * 64;
#pragma unroll
    for (int i = 0; i < 4; ++i) {
        int lin = t + i * 256;
        int r = lin >> 4;
        int c4 = (lin & 15) * 4;
        float inv = 1.0f / ks[r];
        float4 v = *(const float4*)(cb + (size_t)r * DH + c4);
        __align__(8) unsigned short o4[4] = {f2bf(v.x * inv), f2bf(v.y * inv),
                                             f2bf(v.z * inv), f2bf(v.w * inv)};
        int chunk = c4 >> 3;
        int off = (c4 & 7) * 2;
        *(uint2*)((char*)Bs + r * 128 + ((chunk ^ (r & 7)) << 4) + off) = *(const uint2*)o4;
    }
    __syncthreads();

    f32x4 acc[2][4] = {};
#pragma unroll
    for (int s = 0; s < 2; ++s) {
        int chunk = s * 4 + (lane >> 4);
        bf16x8 bf[4];
#pragma unroll
        for (int nf = 0; nf < 4; ++nf) {
            int brow = nf * 16 + (lane & 15);
            bf[nf] = *(const bf16x8*)((const char*)Bs + brow * 128 + ((chunk ^ (brow & 7)) << 4));
        }
#pragma unroll
        for (int mm = 0; mm < 2; ++mm) {
            int arow = (wv * 2 + mm) * 16 + (lane & 15);
            bf16x8 a = *(const bf16x8*)((const char*)As + arow * 128 + ((chunk ^ (arow & 7)) << 4));
#pragma unroll
            for (int nf = 0; nf < 4; ++nf)
                acc[mm][nf] = __builtin_amdgcn_mfma_f32_16x16x32_bf16(a, bf[nf], acc[mm][nf], 0, 0, 0);
        }
    }

#pragma unroll
    for (int mm = 0; mm < 2; ++mm) {
        int o_base = ot * 128 + (wv * 2 + mm) * 16 + (lane >> 4) * 4;
#pragma unroll
        for (int nf = 0; nf < 4; ++nf) {
            int d = nf * 16 + (lane & 15);
#pragma unroll
            for (int rr = 0; rr < 4; ++rr)
                w2[((size_t)(b * D) + o_base + rr) * D + h * 64 + d] = f2bf(acc[mm][nf][rr]);
        }
    }
}

// ---------------------------------------------------------------------------
// gemm_y: y = W2[b] @ qT + bias -> fp32 out, plus per-column sum(y^2) atomics
// ---------------------------------------------------------------------------
__global__ __launch_bounds__(256) void gemm_y(const unsigned short* __restrict__ w2all,
                                              const unsigned short* __restrict__ qTall,
                                              const float* __restrict__ bias,
                                              float* __restrict__ yall,
                                              float* __restrict__ colsum) {
    const int b = blockIdx.z;
    const unsigned short* A = w2all + (size_t)b * D * D;
    const unsigned short* BT = qTall + (size_t)b * N * KDIM;
    float* y = yall + (size_t)b * D * N;
    const int row0 = blockIdx.y * 128;
    const int col0 = blockIdx.x * 128;
    GEMM_CORE_DB(A, BT, acc)

    float csum[4] = {0.f, 0.f, 0.f, 0.f};
#pragma unroll
    for (int m = 0; m < 4; ++m) {
        int row_b = row0 + wm * 64 + m * 16 + (lane >> 4) * 4;
#pragma unroll
        for (int r = 0; r < 4; ++r) {
            float bv = bias[row_b + r];
#pragma unroll
            for (int n = 0; n < 4; ++n) {
                int col = col0 + wn * 64 + n * 16 + (lane & 15);
                float e = acc[m][n][r] + bv;
                y[(size_t)(row_b + r) * N + col] = e;
                csum[n] += e * e;
            }
        }
    }
#pragma unroll
    for (int n = 0; n < 4; ++n) {
        csum[n] += __shfl_xor(csum[n], 16);
        csum[n] += __shfl_xor(csum[n], 32);
    }
    if (lane < 16) {
#pragma unroll
        for (int n = 0; n < 4; ++n) {
            int col = col0 + wn * 64 + n * 16 + lane;
            atomicAdd(&colsum[b * N + col], csum[n]);
        }
    }
}

// ---------------------------------------------------------------------------
// colprep: colsum -> SQRT_D / max(sqrt(colsum), eps)   (B*N elements)
// ---------------------------------------------------------------------------
__global__ __launch_bounds__(256) void colprep(float* __restrict__ cs) {
    int i = blockIdx.x * 256 + threadIdx.x;
    float v = cs[i];
    cs[i] = SQRT_D / fmaxf(sqrtf(v), 1e-12f);
}

// ---------------------------------------------------------------------------
// rmsnorm4: in-place elementwise scale: y *= rinv[b,n] * g[o]
// ---------------------------------------------------------------------------
__global__ __launch_bounds__(256) void rmsnorm4(float4* __restrict__ y,
                                                const float4* __restrict__ rinv,
                                                const float* __restrict__ g) {
    const size_t total = (size_t)B * D * N / 4;
    for (size_t i = blockIdx.x * 256 + threadIdx.x; i < total; i += 524288) {
        int b = (int)(i >> 19);
        int rem = (int)(i & 524287);
        int o = rem >> 10;
        int n4 = rem & 1023;
        float4 v = y[i];
        float4 rv = rinv[b * 1024 + n4];
        float go = g[o];
        v.x *= rv.x * go;
        v.y *= rv.y * go;
        v.z *= rv.z * go;
        v.w *= rv.w * go;
        y[i] = v;
    }
}

extern "C" void kernel_launch(void* const* d_in, const int* in_sizes, int n_in,
                              void* d_out, int out_size, void* d_ws, size_t ws_size,
                              hipStream_t stream) {
    const float* x = (const float*)d_in[0];
    const float* w_qkv = (const float*)d_in[1];
    const float* w_out = (const float*)d_in[2];
    const float* b_out = (const float*)d_in[3];
    const float* g = (const float*)d_in[4];
    float* out = (float*)d_out;

    // workspace layout
    unsigned short* kvb = (unsigned short*)d_ws;                 // 64 MB
    float* ctx = (float*)(kvb + (size_t)B * 1024 * N);           // 1 MB
    float* ksum = ctx + (size_t)B * HEADS * DH * DH;             // 16 KB
    float* colsum = ksum + B * 512;                              // 128 KB
    unsigned short* w2 = (unsigned short*)(colsum + B * N);      // 4 MB
    unsigned short* wqb = w2 + (size_t)B * D * D;                // 1.5 MB
    unsigned short* xT = wqb + (size_t)O3 * KDIM;                // 32 MB
    unsigned short* qT = xT + (size_t)B * N * KDIM;              // 32 MB

    // zero ctx + ksum + colsum (contiguous)
    hipMemsetAsync(ctx, 0,
                   ((size_t)B * HEADS * DH * DH + B * 512 + B * N) * sizeof(float), stream);

    cvt_w<<<dim3(O3 * KDIM / 1024), 256, 0, stream>>>(w_qkv, wqb);
    transpose_x<<<dim3(N / 64, D / 64, B), 256, 0, stream>>>(x, xT);

    gemm_qkv<<<dim3(N / 128, O3 / 128, B), 256, 0, stream>>>(wqb, xT, qT, kvb);

    context_mfma3<<<dim3(8, HEADS, B), 256, 0, stream>>>(kvb, ctx, ksum);
    fold_wout3<<<dim3(4, HEADS, B), 256, 0, stream>>>(w_out, ctx, ksum, w2);

    gemm_y<<<dim3(N / 128, D / 128, B), 256, 0, stream>>>(w2, qT, b_out, out, colsum);

    colprep<<<dim3(B * N / 256), 256, 0, stream>>>(colsum);
    rmsnorm4<<<dim3(2048), 256, 0, stream>>>((float4*)out, (const float4*)colsum, g);
}

// Round 10
// 166.146 us; speedup vs baseline: 1.2127x; 1.0183x over previous
//
#include <hip/hip_runtime.h>
#include <math.h>

#define B 8
#define D 512
#define N 4096
#define HEADS 8
#define DH 64
#define HID 512
#define O3 1536
#define KDIM 512
#define SCALE 0.125f
#define SQRT_D 22.62741699796952f

typedef __attribute__((ext_vector_type(4))) float f32x4;
typedef __attribute__((ext_vector_type(8))) short bf16x8;

static __device__ __forceinline__ unsigned short f2bf(float f) {
    unsigned int u = __float_as_uint(f);
    unsigned int r = (u + 0x7fffu + ((u >> 16) & 1u)) >> 16;
    return (unsigned short)r;
}

static __device__ __forceinline__ float bf2f(unsigned short u) {
    return __uint_as_float((unsigned int)u << 16);
}

static __device__ __forceinline__ void gload_lds16(const void* g, void* l) {
    __builtin_amdgcn_global_load_lds(
        (const __attribute__((address_space(1))) unsigned int*)g,
        (__attribute__((address_space(3))) unsigned int*)l, 16, 0, 0);
}

// ---------------------------------------------------------------------------
// cvt_w: w_qkv fp32 [1536*512] -> bf16
// ---------------------------------------------------------------------------
__global__ __launch_bounds__(256) void cvt_w(const float* __restrict__ w,
                                             unsigned short* __restrict__ wb) {
    int i = (blockIdx.x * 256 + threadIdx.x) * 4;
    float4 v = *(const float4*)(w + i);
    __align__(8) unsigned short o[4] = {f2bf(v.x), f2bf(v.y), f2bf(v.z), f2bf(v.w)};
    *(uint2*)(wb + i) = *(const uint2*)o;
}

// ---------------------------------------------------------------------------
// transpose_x: x fp32 [b][512][4096] -> xT bf16 [b][4096][512]
// ---------------------------------------------------------------------------
__global__ __launch_bounds__(256) void transpose_x(const float* __restrict__ x,
                                                   unsigned short* __restrict__ xT) {
    __shared__ float tile[64][65];
    const int n0 = blockIdx.x * 64, d0 = blockIdx.y * 64, b = blockIdx.z;
    const float* xb = x + (size_t)b * D * N;
    unsigned short* xTb = xT + (size_t)b * N * KDIM;
    const int t = threadIdx.x;
    const int r = t >> 4, c4 = (t & 15) * 4;
#pragma unroll
    for (int i = 0; i < 4; ++i) {
        int row = r + i * 16;
        float4 v = *(const float4*)(xb + (size_t)(d0 + row) * N + n0 + c4);
        tile[row][c4 + 0] = v.x;
        tile[row][c4 + 1] = v.y;
        tile[row][c4 + 2] = v.z;
        tile[row][c4 + 3] = v.w;
    }
    __syncthreads();
#pragma unroll
    for (int pass = 0; pass < 2; ++pass) {
        int orow = (t >> 3) + pass * 32;
        int oc = (t & 7) * 8;
        __align__(16) unsigned short o[8];
#pragma unroll
        for (int e = 0; e < 8; ++e) o[e] = f2bf(tile[oc + e][orow]);
        *(uint4*)(xTb + (size_t)(n0 + orow) * KDIM + d0 + oc) = *(const uint4*)o;
    }
}

// ---------------------------------------------------------------------------
// T4 pipelined GEMM core: 128x128 tile, BK=64, 4 waves, double-buffered LDS,
// raw s_barrier + counted vmcnt (prefetch loads stay in flight across the
// barrier — __syncthreads would drain them).
// Per-wave vm ops per stage = 8. Iteration kt: reads buf[kt&1] (landed:
// vmcnt(8) leaves only stage(kt+1)'s 8 outstanding), stages buf[(kt+1)&1]
// (its prior readers sealed by iteration kt-1's second barrier).
// ---------------------------------------------------------------------------
#define STAGE_AB(A_PTR, BT_PTR, BUFOFF, KOFF)                                      \
    _Pragma("unroll") for (int i = 0; i < 4; ++i)                                  \
        gload_lds16(A_PTR + (size_t)(row0 + prow[i]) * KDIM + (KOFF) + coff[i],    \
                    (char*)As + (BUFOFF) + i * 4096 + t * 16);                     \
    _Pragma("unroll") for (int i = 0; i < 4; ++i)                                  \
        gload_lds16(BT_PTR + (size_t)(col0 + prow[i]) * KDIM + (KOFF) + coff[i],   \
                    (char*)Bs + (BUFOFF) + i * 4096 + t * 16);

#define GEMM_CORE_DB(A_PTR, BT_PTR, ACC)                                           \
    __shared__ __align__(16) unsigned short As[2 * 128 * 64];                      \
    __shared__ __align__(16) unsigned short Bs[2 * 128 * 64];                      \
    const int t = threadIdx.x;                                                     \
    const int lane = t & 63;                                                       \
    const int wid = t >> 6;                                                        \
    const int wm = wid >> 1, wn = wid & 1;                                         \
    int prow[4], coff[4];                                                          \
    _Pragma("unroll") for (int i = 0; i < 4; ++i) {                                \
        int p = i * 4096 + t * 16;                                                 \
        int pr = p >> 7;                                                           \
        int pc = (p >> 4) & 7;                                                     \
        prow[i] = pr;                                                              \
        coff[i] = (pc ^ (pr & 7)) * 8;                                             \
    }                                                                              \
    int aoff[4][2], boff[4][2];                                                    \
    _Pragma("unroll") for (int m = 0; m < 4; ++m) {                                \
        int arow = wm * 64 + m * 16 + (lane & 15);                                 \
        int brow = wn * 64 + m * 16 + (lane & 15);                                 \
        _Pragma("unroll") for (int s = 0; s < 2; ++s) {                            \
            int chunk = s * 4 + (lane >> 4);                                       \
            aoff[m][s] = arow * 128 + ((chunk ^ (arow & 7)) << 4);                 \
            boff[m][s] = brow * 128 + ((chunk ^ (brow & 7)) << 4);                 \
        }                                                                          \
    }                                                                              \
    f32x4 ACC[4][4] = {};                                                          \
    { STAGE_AB(A_PTR, BT_PTR, 0, 0) }                                              \
    for (int kt = 0; kt < 8; ++kt) {                                               \
        if (kt < 7) {                                                              \
            STAGE_AB(A_PTR, BT_PTR, ((kt + 1) & 1) * 16384, (kt + 1) * 64)         \
            asm volatile("s_waitcnt vmcnt(8)" ::: "memory");                       \
        } else {                                                                   \
            asm volatile("s_waitcnt vmcnt(0)" ::: "memory");                       \
        }                                                                          \
        __builtin_amdgcn_s_barrier();                                              \
        const int bo = (kt & 1) * 16384;                                           \
        bf16x8 af[4][2], bfr[4][2];                                                \
        _Pragma("unroll") for (int m = 0; m < 4; ++m)                              \
            _Pragma("unroll") for (int s = 0; s < 2; ++s) {                        \
                af[m][s] = *(const bf16x8*)((const char*)As + bo + aoff[m][s]);    \
                bfr[m][s] = *(const bf16x8*)((const char*)Bs + bo + boff[m][s]);   \
            }                                                                      \
        asm volatile("s_waitcnt lgkmcnt(0)" ::: "memory");                         \
        __builtin_amdgcn_sched_barrier(0);                                         \
        __builtin_amdgcn_s_barrier();                                              \
        _Pragma("unroll") for (int s = 0; s < 2; ++s)                              \
            _Pragma("unroll") for (int m = 0; m < 4; ++m)                          \
                _Pragma("unroll") for (int n = 0; n < 4; ++n)                      \
                    ACC[m][n] = __builtin_amdgcn_mfma_f32_16x16x32_bf16(           \
                        af[m][s], bfr[n][s], ACC[m][n], 0, 0, 0);                  \
    }

// ---------------------------------------------------------------------------
// gemm_qkv: fused qkv = w_qkv @ x.
// blockIdx.y < 4: q rows, softmax over d per head -> qT bf16 [b][n][512]
// blockIdx.y >= 4: k,v rows -> bf16 kvb [b][1024][N]
// ---------------------------------------------------------------------------
__global__ __launch_bounds__(256) void gemm_qkv(const unsigned short* __restrict__ Aw,
                                                const unsigned short* __restrict__ BTall,
                                                unsigned short* __restrict__ qT,
                                                unsigned short* __restrict__ kvall) {
    const int b = blockIdx.z;
    const unsigned short* A = Aw;
    const unsigned short* BT = BTall + (size_t)b * N * KDIM;
    const int row0 = blockIdx.y * 128;
    const int col0 = blockIdx.x * 128;
    GEMM_CORE_DB(A, BT, acc)

    if (blockIdx.y < 4) {
        const int h = blockIdx.y * 2 + wm;
        const int g = lane >> 4;
#pragma unroll
        for (int nf = 0; nf < 4; ++nf) {
            float mx = -1e30f;
#pragma unroll
            for (int m = 0; m < 4; ++m)
#pragma unroll
                for (int r = 0; r < 4; ++r) mx = fmaxf(mx, acc[m][nf][r]);
            mx = fmaxf(mx, __shfl_xor(mx, 16));
            mx = fmaxf(mx, __shfl_xor(mx, 32));
            float e[16];
            float s = 0.f;
#pragma unroll
            for (int m = 0; m < 4; ++m)
#pragma unroll
                for (int r = 0; r < 4; ++r) {
                    e[m * 4 + r] = __expf(acc[m][nf][r] - mx);
                    s += e[m * 4 + r];
                }
            s += __shfl_xor(s, 16);
            s += __shfl_xor(s, 32);
            float rs = SCALE / s;
            int n = col0 + wn * 64 + nf * 16 + (lane & 15);
            unsigned short* dst = qT + ((size_t)b * N + n) * KDIM + h * 64 + g * 4;
#pragma unroll
            for (int m = 0; m < 4; ++m) {
                __align__(8) unsigned short o4[4] = {
                    f2bf(e[m * 4 + 0] * rs), f2bf(e[m * 4 + 1] * rs),
                    f2bf(e[m * 4 + 2] * rs), f2bf(e[m * 4 + 3] * rs)};
                *(uint2*)(dst + m * 16) = *(const uint2*)o4;
            }
        }
    } else {
        unsigned short* C = kvall + (size_t)b * 1024 * N;
        const int rbase = row0 - 512;
#pragma unroll
        for (int m = 0; m < 4; ++m) {
            int row_b = rbase + wm * 64 + m * 16 + (lane >> 4) * 4;
#pragma unroll
            for (int n = 0; n < 4; ++n) {
                int col = col0 + wn * 64 + n * 16 + (lane & 15);
#pragma unroll
                for (int r = 0; r < 4; ++r)
                    C[(size_t)(row_b + r) * N + col] = f2bf(acc[m][n][r]);
            }
        }
    }
}

// ---------------------------------------------------------------------------
// context_mfma3: per (b,h,chunk): ctx[d][e] += sum_n exp(k[d,n]) * v[e,n]
// plus ksum[d] += sum_n exp(k[d,n]) via MFMA against a ones vector.
// ---------------------------------------------------------------------------
__global__ __launch_bounds__(256) void context_mfma3(const unsigned short* __restrict__ kvb,
                                                     float* __restrict__ ctx,
                                                     float* __restrict__ ksum) {
    const int ch = blockIdx.x, h = blockIdx.y, b = blockIdx.z;
    const int K0 = ch * 512;
    const unsigned short* kbase = kvb + ((size_t)b * 1024 + h * DH) * (size_t)N + K0;
    const unsigned short* vbase = kvb + ((size_t)b * 1024 + 512 + h * DH) * (size_t)N + K0;

    __shared__ __align__(16) unsigned short Ks[64 * 64];
    __shared__ __align__(16) unsigned short Vs[64 * 64];

    const int t = threadIdx.x;
    const int lane = t & 63;
    const int wv = t >> 6;

    const int kr = t >> 2;
    const int kc = (t & 3) * 16;
    const int kchunk0 = kc >> 3;
    const int kdst0 = kr * 128 + (((kchunk0 + 0) ^ (kr & 7)) << 4);
    const int kdst1 = kr * 128 + (((kchunk0 + 1) ^ (kr & 7)) << 4);

    int vrow[2], vcoff[2];
#pragma unroll
    for (int i = 0; i < 2; ++i) {
        int p = i * 4096 + t * 16;
        int pr = p >> 7;
        int pc = (p >> 4) & 7;
        vrow[i] = pr;
        vcoff[i] = (pc ^ (pr & 7)) * 8;
    }

    const int ar = wv * 16 + (lane & 15);
    int aoff[2], boff[4][2];
#pragma unroll
    for (int s = 0; s < 2; ++s) {
        int chunk = s * 4 + (lane >> 4);
        aoff[s] = ar * 128 + ((chunk ^ (ar & 7)) << 4);
#pragma unroll
        for (int nf = 0; nf < 4; ++nf) {
            int br = nf * 16 + (lane & 15);
            boff[nf][s] = br * 128 + ((chunk ^ (br & 7)) << 4);
        }
    }

    bf16x8 ones;
#pragma unroll
    for (int j = 0; j < 8; ++j) ones[j] = (short)0x3F80;

    f32x4 acc[4] = {};
    f32x4 accs = {};

    for (int k0 = 0; k0 < 512; k0 += 64) {
#pragma unroll
        for (int i = 0; i < 2; ++i)
            gload_lds16(vbase + (size_t)vrow[i] * N + k0 + vcoff[i],
                        (char*)Vs + i * 4096 + t * 16);
        __align__(16) unsigned short raw[16];
        *(uint4*)raw = *(const uint4*)(kbase + (size_t)kr * N + k0 + kc);
        *(uint4*)(raw + 8) = *(const uint4*)(kbase + (size_t)kr * N + k0 + kc + 8);
        __align__(16) unsigned short o[16];
#pragma unroll
        for (int j = 0; j < 16; ++j) o[j] = f2bf(__expf(bf2f(raw[j])));
        *(uint4*)((char*)Ks + kdst0) = *(const uint4*)o;
        *(uint4*)((char*)Ks + kdst1) = *(const uint4*)(o + 8);
        __syncthreads();

        bf16x8 av[2], bv[4][2];
#pragma unroll
        for (int s = 0; s < 2; ++s) {
            av[s] = *(const bf16x8*)((const char*)Ks + aoff[s]);
#pragma unroll
            for (int nf = 0; nf < 4; ++nf)
                bv[nf][s] = *(const bf16x8*)((const char*)Vs + boff[nf][s]);
        }
#pragma unroll
        for (int s = 0; s < 2; ++s) {
#pragma unroll
            for (int nf = 0; nf < 4; ++nf)
                acc[nf] = __builtin_amdgcn_mfma_f32_16x16x32_bf16(av[s], bv[nf][s], acc[nf], 0, 0, 0);
            accs = __builtin_amdgcn_mfma_f32_16x16x32_bf16(av[s], ones, accs, 0, 0, 0);
        }
        __syncthreads();
    }

    float* cbase = ctx + ((size_t)(b * HEADS + h)) * DH * DH;
    const int drow = wv * 16 + (lane >> 4) * 4;
#pragma unroll
    for (int nf = 0; nf < 4; ++nf) {
        int e = nf * 16 + (lane & 15);
#pragma unroll
        for (int rr = 0; rr < 4; ++rr)
            atomicAdd(&cbase[(drow + rr) * DH + e], acc[nf][rr]);
    }
    if ((lane & 15) == 0) {
#pragma unroll
        for (int rr = 0; rr < 4; ++rr)
            atomicAdd(&ksum[b * 512 + h * DH + drow + rr], accs[rr]);
    }
}

// ---------------------------------------------------------------------------
// fold_wout3: per (b,h): W2[o][d] = sum_e w_out[o][h*64+e] * ctx[b,h,d,e]/ksum[d]
// ---------------------------------------------------------------------------
__global__ __launch_bounds__(256) void fold_wout3(const float* __restrict__ w_out,
                                                  const float* __restrict__ ctx,
                                                  const float* __restrict__ ksum,
                                                  unsigned short* __restrict__ w2) {
    const int ot = blockIdx.x, h = blockIdx.y, b = blockIdx.z;
    __shared__ __align__(16) unsigned short As[128 * 64];
    __shared__ __align__(16) unsigned short Bs[64 * 64];
    const int t = threadIdx.x;
    const int lane = t & 63;
    const int wv = t >> 6;

#pragma unroll
    for (int i = 0; i < 8; ++i) {
        int lin = t + i * 256;
        int r = lin >> 4;
        int c4 = (lin & 15) * 4;
        float4 v = *(const float4*)(w_out + (size_t)(ot * 128 + r) * HID + h * 64 + c4);
        __align__(8) unsigned short o4[4] = {f2bf(v.x), f2bf(v.y), f2bf(v.z), f2bf(v.w)};
        int chunk = c4 >> 3;
        int off = (c4 & 7) * 2;
        *(uint2*)((char*)As + r * 128 + ((chunk ^ (r & 7)) << 4) + off) = *(const uint2*)o4;
    }
    const float* cb = ctx + ((size_t)(b * HEADS + h)) * DH * DH;
    const float* ks = ksum + b * 512 + h * 64;
#pragma unroll
    for (int i = 0; i < 4; ++i) {
        int lin = t + i * 256;
        int r = lin >> 4;
        int c4 = (lin & 15) * 4;
        float inv = 1.0f / ks[r];
        float4 v = *(const float4*)(cb + (size_t)r * DH + c4);
        __align__(8) unsigned short o4[4] = {f2bf(v.x * inv), f2bf(v.y * inv),
                                             f2bf(v.z * inv), f2bf(v.w * inv)};
        int chunk = c4 >> 3;
        int off = (c4 & 7) * 2;
        *(uint2*)((char*)Bs + r * 128 + ((chunk ^ (r & 7)) << 4) + off) = *(const uint2*)o4;
    }
    __syncthreads();

    f32x4 acc[2][4] = {};
#pragma unroll
    for (int s = 0; s < 2; ++s) {
        int chunk = s * 4 + (lane >> 4);
        bf16x8 bf[4];
#pragma unroll
        for (int nf = 0; nf < 4; ++nf) {
            int brow = nf * 16 + (lane & 15);
            bf[nf] = *(const bf16x8*)((const char*)Bs + brow * 128 + ((chunk ^ (brow & 7)) << 4));
        }
#pragma unroll
        for (int mm = 0; mm < 2; ++mm) {
            int arow = (wv * 2 + mm) * 16 + (lane & 15);
            bf16x8 a = *(const bf16x8*)((const char*)As + arow * 128 + ((chunk ^ (arow & 7)) << 4));
#pragma unroll
            for (int nf = 0; nf < 4; ++nf)
                acc[mm][nf] = __builtin_amdgcn_mfma_f32_16x16x32_bf16(a, bf[nf], acc[mm][nf], 0, 0, 0);
        }
    }

#pragma unroll
    for (int mm = 0; mm < 2; ++mm) {
        int o_base = ot * 128 + (wv * 2 + mm) * 16 + (lane >> 4) * 4;
#pragma unroll
        for (int nf = 0; nf < 4; ++nf) {
            int d = nf * 16 + (lane & 15);
#pragma unroll
            for (int rr = 0; rr < 4; ++rr)
                w2[((size_t)(b * D) + o_base + rr) * D + h * 64 + d] = f2bf(acc[mm][nf][rr]);
        }
    }
}

// ---------------------------------------------------------------------------
// gemm_y: y = W2[b] @ qT + bias -> fp32 out, plus per-column sum(y^2) atomics
// ---------------------------------------------------------------------------
__global__ __launch_bounds__(256) void gemm_y(const unsigned short* __restrict__ w2all,
                                              const unsigned short* __restrict__ qTall,
                                              const float* __restrict__ bias,
                                              float* __restrict__ yall,
                                              float* __restrict__ colsum) {
    const int b = blockIdx.z;
    const unsigned short* A = w2all + (size_t)b * D * D;
    const unsigned short* BT = qTall + (size_t)b * N * KDIM;
    float* y = yall + (size_t)b * D * N;
    const int row0 = blockIdx.y * 128;
    const int col0 = blockIdx.x * 128;
    GEMM_CORE_DB(A, BT, acc)

    float csum[4] = {0.f, 0.f, 0.f, 0.f};
#pragma unroll
    for (int m = 0; m < 4; ++m) {
        int row_b = row0 + wm * 64 + m * 16 + (lane >> 4) * 4;
#pragma unroll
        for (int r = 0; r < 4; ++r) {
            float bv = bias[row_b + r];
#pragma unroll
            for (int n = 0; n < 4; ++n) {
                int col = col0 + wn * 64 + n * 16 + (lane & 15);
                float e = acc[m][n][r] + bv;
                y[(size_t)(row_b + r) * N + col] = e;
                csum[n] += e * e;
            }
        }
    }
#pragma unroll
    for (int n = 0; n < 4; ++n) {
        csum[n] += __shfl_xor(csum[n], 16);
        csum[n] += __shfl_xor(csum[n], 32);
    }
    if (lane < 16) {
#pragma unroll
        for (int n = 0; n < 4; ++n) {
            int col = col0 + wn * 64 + n * 16 + lane;
            atomicAdd(&colsum[b * N + col], csum[n]);
        }
    }
}

// ---------------------------------------------------------------------------
// colprep: colsum -> SQRT_D / max(sqrt(colsum), eps)   (B*N elements)
// ---------------------------------------------------------------------------
__global__ __launch_bounds__(256) void colprep(float* __restrict__ cs) {
    int i = blockIdx.x * 256 + threadIdx.x;
    float v = cs[i];
    cs[i] = SQRT_D / fmaxf(sqrtf(v), 1e-12f);
}

// ---------------------------------------------------------------------------
// rmsnorm4: in-place elementwise scale: y *= rinv[b,n] * g[o]
// ---------------------------------------------------------------------------
__global__ __launch_bounds__(256) void rmsnorm4(float4* __restrict__ y,
                                                const float4* __restrict__ rinv,
                                                const float* __restrict__ g) {
    const size_t total = (size_t)B * D * N / 4;
    for (size_t i = blockIdx.x * 256 + threadIdx.x; i < total; i += 524288) {
        int b = (int)(i >> 19);
        int rem = (int)(i & 524287);
        int o = rem >> 10;
        int n4 = rem & 1023;
        float4 v = y[i];
        float4 rv = rinv[b * 1024 + n4];
        float go = g[o];
        v.x *= rv.x * go;
        v.y *= rv.y * go;
        v.z *= rv.z * go;
        v.w *= rv.w * go;
        y[i] = v;
    }
}

extern "C" void kernel_launch(void* const* d_in, const int* in_sizes, int n_in,
                              void* d_out, int out_size, void* d_ws, size_t ws_size,
                              hipStream_t stream) {
    const float* x = (const float*)d_in[0];
    const float* w_qkv = (const float*)d_in[1];
    const float* w_out = (const float*)d_in[2];
    const float* b_out = (const float*)d_in[3];
    const float* g = (const float*)d_in[4];
    float* out = (float*)d_out;

    // workspace layout
    unsigned short* kvb = (unsigned short*)d_ws;                 // 64 MB
    float* ctx = (float*)(kvb + (size_t)B * 1024 * N);           // 1 MB
    float* ksum = ctx + (size_t)B * HEADS * DH * DH;             // 16 KB
    float* colsum = ksum + B * 512;                              // 128 KB
    unsigned short* w2 = (unsigned short*)(colsum + B * N);      // 4 MB
    unsigned short* wqb = w2 + (size_t)B * D * D;                // 1.5 MB
    unsigned short* xT = wqb + (size_t)O3 * KDIM;                // 32 MB
    unsigned short* qT = xT + (size_t)B * N * KDIM;              // 32 MB

    // zero ctx + ksum + colsum (contiguous)
    hipMemsetAsync(ctx, 0,
                   ((size_t)B * HEADS * DH * DH + B * 512 + B * N) * sizeof(float), stream);

    cvt_w<<<dim3(O3 * KDIM / 1024), 256, 0, stream>>>(w_qkv, wqb);
    transpose_x<<<dim3(N / 64, D / 64, B), 256, 0, stream>>>(x, xT);

    gemm_qkv<<<dim3(N / 128, O3 / 128, B), 256, 0, stream>>>(wqb, xT, qT, kvb);

    context_mfma3<<<dim3(8, HEADS, B), 256, 0, stream>>>(kvb, ctx, ksum);
    fold_wout3<<<dim3(4, HEADS, B), 256, 0, stream>>>(w_out, ctx, ksum, w2);

    gemm_y<<<dim3(N / 128, D / 128, B), 256, 0, stream>>>(w2, qT, b_out, out, colsum);

    colprep<<<dim3(B * N / 256), 256, 0, stream>>>(colsum);
    rmsnorm4<<<dim3(2048), 256, 0, stream>>>((float4*)out, (const float4*)colsum, g);
}